// Round 3
// baseline (216.098 us; speedup 1.0000x reference)
//
#include <hip/hip_runtime.h>
#include <hip/hip_bf16.h>

#define B_  512
#define L_  100
#define D_  128
#define SP_ 136      // Pt ushort stride
#define SO_ 132      // Ot float stride (528 B rows: 16B-aligned, 2-way max bank alias)

typedef unsigned short ushort_t;
typedef __attribute__((ext_vector_type(8))) unsigned short us8;
typedef __attribute__((ext_vector_type(8))) __bf16 bf8;
typedef __attribute__((ext_vector_type(4))) float f4;
typedef __attribute__((ext_vector_type(4))) float f4v;
typedef __attribute__((ext_vector_type(4))) unsigned int ui4;

__device__ __forceinline__ float b2f(ushort_t u) {
  union { unsigned i; float f; } v; v.i = ((unsigned)u) << 16; return v.f;
}
__device__ __forceinline__ ushort_t f2b(float f) {
  unsigned u = __float_as_uint(f);
  u += 0x7fffu + ((u >> 16) & 1u);   // RNE
  return (ushort_t)(u >> 16);
}
__device__ __forceinline__ us8 pack8(const float* x) {
  union { __hip_bfloat162 h; unsigned u; } cv;
  ui4 pk;
#pragma unroll
  for (int t = 0; t < 4; ++t) {
    cv.h = __float22bfloat162_rn(make_float2(x[2 * t], x[2 * t + 1]));
    pk[t] = cv.u;
  }
  return __builtin_bit_cast(us8, pk);
}
// XOR-swizzled Hs index (16B chunks contiguous; chunk ^= row&15)
__device__ __forceinline__ int sw(int row, int col) {
  return row * 128 + ((((col >> 3) ^ row) & 15) << 3) + (col & 7);
}

// One block per batch, 448 threads = 7 waves; wave w owns M-tile w.
// smem pool carve (bytes):
//   [0,     32768)  Hs   128x128 bf16 swizzled (later: H^T; later: aliased by Ot)
//   [32768, 63232)  Pt   7 x 16 x SP_ bf16     (later: aliased by Ot)
//   [63232, 65280)  aVf  4x128 f32
// Ot (f32, stride SO_, 59136 B) aliases [0, 59136) after the PV-read barrier.
//
// Latency-structure version (r3):
//  - emb gather manually unrolled x5: all idx loads issue, then all emb
//    loads, then converts (kills the serial idx->emb->convert chain)
//  - adj edge types loaded direct global->regs at kernel top (hidden
//    under gather); adjS LDS region removed
//  - E phase: two fully-unrolled 2-head passes (Af2=32 VGPR live,
//    cndmask lg updates, sched_barrier between passes) -> halves B-side
//    LDS reads vs 4-pass r2 while staying under the 128-reg cap
//  - transpose split read-all->regs / barrier / write-all; reads issue
//    before softmax so their latency hides under softmax VALU
__global__ __launch_bounds__(448, 4)
void CombineGraph_fused(const int* __restrict__ inp, const int* __restrict__ adjG,
                        const float* __restrict__ embF,
                        const float* __restrict__ a0F, const float* __restrict__ a1F,
                        const float* __restrict__ a2F, const float* __restrict__ a3F,
                        float* __restrict__ outG) {
  __shared__ __align__(16) unsigned char smem[65280];
  ushort_t* Hs = (ushort_t*)smem;
  ushort_t* Pt = (ushort_t*)(smem + 32768);
  float* aVf = (float*)(smem + 63232);

  const int b = blockIdx.x, tid = threadIdx.x;
  const int w = tid / 64, lane = tid & 63, c = lane & 15, q = lane >> 4;
  const int mi = w;

  // ---- 1) issue all emb row-index loads (5 guarded, unrolled) ----
  int idxv[5];
#pragma unroll
  for (int it = 0; it < 5; ++it) {
    int u = tid + it * 448;
    int r = u >> 4;
    idxv[it] = (u < 2048 && r < L_) ? inp[b * L_ + r] : 0;
  }

  // ---- 2) issue all emb row loads (10 x b128, unrolled) ----
  f4v ev0[5], ev1[5];
#pragma unroll
  for (int it = 0; it < 5; ++it) {
    int u = tid + it * 448;
    int r = u >> 4, ch = u & 15;
    if (u < 2048 && r < L_) {
      const float* src = embF + ((size_t)idxv[it] << 7) + ch * 8;
      ev0[it] = *(const f4v*)src;
      ev1[it] = *(const f4v*)(src + 4);
    }
  }

  // ---- 3) adj edge types straight to registers (consumed post-barrier) ----
  int tv[7][4];
#pragma unroll
  for (int nt = 0; nt < 7; ++nt) {
    int j = nt * 16 + c;
    int jc = (j < L_) ? j : L_ - 1;
#pragma unroll
    for (int r4 = 0; r4 < 4; ++r4) {
      int i = mi * 16 + q * 4 + r4;
      int ic = (i < L_) ? i : L_ - 1;
      tv[nt][r4] = adjG[(size_t)b * 10000 + ic * 100 + jc];
    }
  }

  // ---- 4) stage a_k vectors ----
  for (int u = tid; u < 512; u += 448) {
    int k = u >> 7, d = u & 127;
    const float* ak = (k == 0) ? a0F : (k == 1) ? a1F : (k == 2) ? a2F : a3F;
    aVf[u] = ak[d];
  }

  // ---- 5) convert f32 -> bf16, write swizzled Hs (rows >= 100 zero) ----
#pragma unroll
  for (int it = 0; it < 5; ++it) {
    int u = tid + it * 448;
    if (u < 2048) {
      int r = u >> 4, ch = u & 15;
      us8 o = {0, 0, 0, 0, 0, 0, 0, 0};
      if (r < L_) {
        float x[8];
#pragma unroll
        for (int t = 0; t < 4; ++t) { x[t] = ev0[it][t]; x[4 + t] = ev1[it][t]; }
        o = pack8(x);
      }
      *(us8*)&Hs[sw(r, ch * 8)] = o;
    }
  }
  __syncthreads();

  // ---- 6) pack edge types: 4 rows x 7 cols -> 7 bytes-packed u32 ----
  unsigned tpk[7];
#pragma unroll
  for (int nt = 0; nt < 7; ++nt) {
    int j = nt * 16 + c;
    unsigned pk = 0;
#pragma unroll
    for (int r4 = 0; r4 < 4; ++r4) {
      int i = mi * 16 + q * 4 + r4;
      int t = (i < L_ && j < L_) ? tv[nt][r4] : 0;
      pk |= ((unsigned)t) << (8 * r4);
    }
    tpk[nt] = pk;
  }

  float lg[7][4];
#pragma unroll
  for (int nt = 0; nt < 7; ++nt)
#pragma unroll
    for (int r4 = 0; r4 < 4; ++r4) lg[nt][r4] = -9e15f;

  // ---- 7) E phase: two fully-unrolled 2-head passes ----
#pragma unroll
  for (int p = 0; p < 2; ++p) {
    us8 Af2[2][4];   // pass-local: 32 VGPRs
#pragma unroll
    for (int ks = 0; ks < 4; ++ks) {
      us8 hr = *(const us8*)&Hs[sw(mi * 16 + c, ks * 32 + q * 8)];
      float hfv[8];
#pragma unroll
      for (int jj = 0; jj < 8; ++jj) hfv[jj] = b2f(hr[jj]);
#pragma unroll
      for (int kk = 0; kk < 2; ++kk) {
        const float* ap = &aVf[(p * 2 + kk) * 128 + ks * 32 + q * 8];
        f4v av0 = *(const f4v*)ap;
        f4v av1 = *(const f4v*)(ap + 4);
        float pr[8];
#pragma unroll
        for (int t = 0; t < 4; ++t) {
          pr[t]     = hfv[t]     * av0[t];
          pr[4 + t] = hfv[4 + t] * av1[t];
        }
        Af2[kk][ks] = pack8(pr);
      }
    }
#pragma unroll
    for (int nt = 0; nt < 7; ++nt) {
      f4 ac0 = {0, 0, 0, 0}, ac1 = {0, 0, 0, 0};
#pragma unroll
      for (int ks = 0; ks < 4; ++ks) {
        bf8 bb = __builtin_bit_cast(bf8, *(const us8*)&Hs[sw(nt * 16 + c, ks * 32 + q * 8)]);
        ac0 = __builtin_amdgcn_mfma_f32_16x16x32_bf16(__builtin_bit_cast(bf8, Af2[0][ks]), bb, ac0, 0, 0, 0);
        ac1 = __builtin_amdgcn_mfma_f32_16x16x32_bf16(__builtin_bit_cast(bf8, Af2[1][ks]), bb, ac1, 0, 0, 0);
      }
#pragma unroll
      for (int r4 = 0; r4 < 4; ++r4) {
        int t = (int)((tpk[nt] >> (8 * r4)) & 255u);
        float e0 = ac0[r4]; e0 = (e0 > 0.f) ? e0 : 0.2f * e0;   // leaky(0.2)
        float e1 = ac1[r4]; e1 = (e1 > 0.f) ? e1 : 0.2f * e1;
        lg[nt][r4] = (t == 2 * p + 1) ? e0 : lg[nt][r4];
        lg[nt][r4] = (t == 2 * p + 2) ? e1 : lg[nt][r4];
      }
    }
    // keep each pass's Af2 build local (prevent hoisting both -> 64 regs live)
    __builtin_amdgcn_sched_barrier(0);
  }

  // ---- 8) transpose READS of original Hs into regs (latency hidden by 9) ----
  unsigned vt[19];
#pragma unroll
  for (int it = 0; it < 19; ++it) {
    int u = tid + it * 448;
    if (u < 8192) {
      int d0 = u >> 7, j0 = u & 127;
      bool up = (j0 > d0);
      int d = up ? d0 : 127 - d0;
      int j = up ? j0 : 127 - j0;
      unsigned va = Hs[sw(d, j)], vb = Hs[sw(j, d)];
      vt[it] = va | (vb << 16);
    }
  }

  // ---- 9) in-register softmax + Pt writes (overlaps 8's LDS latency) ----
  ushort_t* Pw = Pt + w * 16 * SP_;
#pragma unroll
  for (int r4 = 0; r4 < 4; ++r4) {
    float m = lg[0][r4];
#pragma unroll
    for (int nt = 1; nt < 7; ++nt) m = fmaxf(m, lg[nt][r4]);
#pragma unroll
    for (int off = 1; off <= 8; off <<= 1) m = fmaxf(m, __shfl_xor(m, off, 64));
    float ex[7], s = 0.f;
#pragma unroll
    for (int nt = 0; nt < 7; ++nt) { ex[nt] = __expf(lg[nt][r4] - m); s += ex[nt]; }
#pragma unroll
    for (int off = 1; off <= 8; off <<= 1) s += __shfl_xor(s, off, 64);
    float inv = 1.0f / s;
    int row = q * 4 + r4;
#pragma unroll
    for (int nt = 0; nt < 7; ++nt) Pw[row * SP_ + nt * 16 + c] = f2b(ex[nt] * inv);
  }
#pragma unroll
  for (int t = 0; t < 4; ++t) Pw[c * SP_ + 112 + q * 4 + t] = 0;   // zero K-pad 112..127

  __syncthreads();   // barA: all Hs reads (E + transpose-reads) done; Pt final

  // ---- 10) P fragments (Pt final since barA; issue before transpose writes) ----
  us8 Pf[4];
#pragma unroll
  for (int ks = 0; ks < 4; ++ks)
    Pf[ks] = *(const us8*)&Pw[c * SP_ + ks * 32 + q * 8];

  // ---- 11) transpose WRITES (Hs becomes H^T) ----
#pragma unroll
  for (int it = 0; it < 19; ++it) {
    int u = tid + it * 448;
    if (u < 8192) {
      int d0 = u >> 7, j0 = u & 127;
      bool up = (j0 > d0);
      int d = up ? d0 : 127 - d0;
      int j = up ? j0 : 127 - j0;
      Hs[sw(d, j)] = (ushort_t)(vt[it] >> 16);
      Hs[sw(j, d)] = (ushort_t)(vt[it] & 0xffffu);
    }
  }
  __syncthreads();   // barB: H^T ready

  // ---- 12) PV: accumulate all 8 n-tiles into registers ----
  f4 oc[8];
#pragma unroll
  for (int nt2 = 0; nt2 < 8; ++nt2) {
    f4 a = {0, 0, 0, 0};
#pragma unroll
    for (int ks = 0; ks < 4; ++ks) {
      bf8 ob = __builtin_bit_cast(bf8, *(const us8*)&Hs[sw(nt2 * 16 + c, ks * 32 + q * 8)]);
      a = __builtin_amdgcn_mfma_f32_16x16x32_bf16(__builtin_bit_cast(bf8, Pf[ks]), ob, a, 0, 0, 0);
    }
    oc[nt2] = a;
  }
  __syncthreads();   // barC: all Hs/Pt reads complete block-wide; safe to alias

  // ---- 13) stage to LDS row-major, then fully-coalesced dwordx4 stores ----
  float* Ot = (float*)smem;                    // wave w region: [w*16*SO_, ...)
#pragma unroll
  for (int nt2 = 0; nt2 < 8; ++nt2)
#pragma unroll
    for (int r4 = 0; r4 < 4; ++r4)
      Ot[(w * 16 + q * 4 + r4) * SO_ + nt2 * 16 + c] = oc[nt2][r4];
  // same-wave LDS RAW: compiler inserts lgkmcnt; no barrier needed.
#pragma unroll
  for (int it = 0; it < 8; ++it) {
    int u = it * 64 + lane;                    // wave-local: 16 rows x 32 f4-chunks
    int row16 = u >> 5, col4 = u & 31;
    int i = w * 16 + row16;
    if (i < L_) {
      f4 vv = *(const f4*)&Ot[(w * 16 + row16) * SO_ + col4 * 4];
      *(f4*)&outG[((size_t)b * L_ + i) * D_ + col4 * 4] = vv;
    }
  }
}

extern "C" void kernel_launch(void* const* d_in, const int* in_sizes, int n_in,
                              void* d_out, int out_size, void* d_ws, size_t ws_size,
                              hipStream_t stream) {
  (void)d_ws; (void)ws_size; (void)out_size;
  const int* inp = nullptr; const int* adj = nullptr;
  const float* emb = nullptr; const float* aP[4] = {nullptr, nullptr, nullptr, nullptr};
  int na = 0;
  for (int i = 0; i < n_in; ++i) {
    int s = in_sizes[i];
    if (s == 25600000)            emb = (const float*)d_in[i];
    else if (s == 5120000)        adj = (const int*)d_in[i];
    else if (s == 128 && na < 4)  aP[na++] = (const float*)d_in[i];
    else if (s == 51200 && !inp)  inp = (const int*)d_in[i];
  }
  CombineGraph_fused<<<dim3(B_), dim3(448), 0, stream>>>(
      inp, adj, emb, aP[0], aP[1], aP[2], aP[3], (float*)d_out);
}

// Round 9
// 188.597 us; speedup vs baseline: 1.1458x; 1.1458x over previous
//
#include <hip/hip_runtime.h>
#include <hip/hip_bf16.h>

#define B_  512
#define L_  100
#define D_  128
#define SP_ 136      // Pt ushort stride
#define SO_ 132      // Ot float stride (528 B rows: 16B-aligned, 2-way max bank alias)

typedef unsigned short ushort_t;
typedef __attribute__((ext_vector_type(8))) unsigned short us8;
typedef __attribute__((ext_vector_type(8))) __bf16 bf8;
typedef __attribute__((ext_vector_type(4))) float f4;
typedef __attribute__((ext_vector_type(4))) float f4v;
typedef __attribute__((ext_vector_type(4))) int i4v;
typedef __attribute__((ext_vector_type(4))) unsigned int ui4;

__device__ __forceinline__ float b2f(ushort_t u) {
  union { unsigned i; float f; } v; v.i = ((unsigned)u) << 16; return v.f;
}
__device__ __forceinline__ ushort_t f2b(float f) {
  unsigned u = __float_as_uint(f);
  u += 0x7fffu + ((u >> 16) & 1u);   // RNE
  return (ushort_t)(u >> 16);
}
__device__ __forceinline__ us8 pack8(const float* x) {
  union { __hip_bfloat162 h; unsigned u; } cv;
  ui4 pk;
#pragma unroll
  for (int t = 0; t < 4; ++t) {
    cv.h = __float22bfloat162_rn(make_float2(x[2 * t], x[2 * t + 1]));
    pk[t] = cv.u;
  }
  return __builtin_bit_cast(us8, pk);
}
// XOR-swizzled Hs index (16B chunks contiguous; chunk ^= row&15)
__device__ __forceinline__ int sw(int row, int col) {
  return row * 128 + ((((col >> 3) ^ row) & 15) << 3) + (col & 7);
}

// One block per batch, 448 threads = 7 waves; wave w owns M-tile w.
// smem pool carve (bytes):
//   [0,     32768)  Hs   128x128 bf16 swizzled (later: H^T; later: aliased by Ot)
//   [32768, 63232)  Pt   7 x 16 x SP_ bf16     (later: aliased by Ot)
//   [63232, 73232)  adjS 100x100 u8
//   [73232, 75280)  aVf  4x128 f32
// Ot (f32, stride SO_, 59136 B) aliases [0, 59136) after the PV barrier.
//
// r9 = r2 proven skeleton (E 4-pass head-outer / softmax / IN-PLACE
// transpose / PV, all sw()-swizzled; full harness run at ~48us/dispatch)
// + ONE zero-novel-semantics latency fix:
//   * phase-0 pipelined with bounded registers (idx5 -> adj6-deep ->
//     pack/store -> fence -> emb5-deep -> convert); kills the per-iter
//     idx->emb->convert serial chain of r2's strided loops. This exact
//     phase-0 compiled+ran on HW in r4/r5 (their failures were PV
//     tr-read numerics only).
// The r6 split-transpose is deliberately dropped this round to bisect
// the repeated container failures: this source is ~95% r2 bytes.
// Register discipline: every phase's arch-VGPR live set <= ~60
// (empirical spill line at 64 arch; r0/r1/r3 spilled past it).
__global__ __launch_bounds__(448, 4)
void CombineGraph_fused(const int* __restrict__ inp, const int* __restrict__ adjG,
                        const float* __restrict__ embF,
                        const float* __restrict__ a0F, const float* __restrict__ a1F,
                        const float* __restrict__ a2F, const float* __restrict__ a3F,
                        float* __restrict__ outG) {
  __shared__ __align__(16) unsigned char smem[75280];
  ushort_t* Hs = (ushort_t*)smem;
  ushort_t* Pt = (ushort_t*)(smem + 32768);
  unsigned char* adjS = smem + 63232;
  float* aVf = (float*)(smem + 73232);

  const int b = blockIdx.x, tid = threadIdx.x;
  const int w = tid / 64, lane = tid & 63, c = lane & 15, q = lane >> 4;
  const int mi = w;

  // ---- phase 0a: issue emb row-index loads (5 regs) ----
  int idxv[5];
#pragma unroll
  for (int it = 0; it < 5; ++it) {
    int u = tid + it * 448;
    int r = u >> 4;
    idxv[it] = (u < 2048 && r < L_) ? inp[b * L_ + r] : 0;
  }

  // ---- phase 0b: adj loads 6-deep (24 regs; peak ~29 with idxv) ----
  i4v av[6];
#pragma unroll
  for (int it = 0; it < 6; ++it) {
    int u = tid + it * 448;
    if (u < 2500) av[it] = *(const i4v*)(adjG + (size_t)b * 10000 + u * 4);
  }

  // ---- phase 0c: stage a_k vectors ----
  for (int u = tid; u < 512; u += 448) {
    int k = u >> 7, d = u & 127;
    const float* ak = (k == 0) ? a0F : (k == 1) ? a1F : (k == 2) ? a2F : a3F;
    aVf[u] = ak[d];
  }

  // ---- phase 0d: pack adj -> uchar4, store to LDS; frees the 24 regs ----
#pragma unroll
  for (int it = 0; it < 6; ++it) {
    int u = tid + it * 448;
    if (u < 2500) {
      i4v v = av[it];
      unsigned pk = (unsigned)(v[0] & 255) | ((unsigned)(v[1] & 255) << 8) |
                    ((unsigned)(v[2] & 255) << 16) | ((unsigned)(v[3] & 255) << 24);
      *(unsigned*)&adjS[u * 4] = pk;
    }
  }
  // fence: keep emb loads below (prevents adj(24) + ev(40) stacking > 64 regs)
  __builtin_amdgcn_sched_barrier(0);

  // ---- phase 0e: emb loads 5-deep (40 regs; nothing else live) ----
  f4v ev0[5], ev1[5];
#pragma unroll
  for (int it = 0; it < 5; ++it) {
    int u = tid + it * 448;
    int r = u >> 4, ch = u & 15;
    if (u < 2048 && r < L_) {
      const float* src = embF + ((size_t)idxv[it] << 7) + ch * 8;
      ev0[it] = *(const f4v*)src;
      ev1[it] = *(const f4v*)(src + 4);
    }
  }
  // ---- phase 0f: convert f32 -> bf16, store swizzled (rows >= 100 zero) ----
#pragma unroll
  for (int it = 0; it < 5; ++it) {
    int u = tid + it * 448;
    if (u < 2048) {
      int r = u >> 4, ch = u & 15;
      us8 o = {0, 0, 0, 0, 0, 0, 0, 0};
      if (r < L_) {
        float x[8];
#pragma unroll
        for (int t = 0; t < 4; ++t) { x[t] = ev0[it][t]; x[4 + t] = ev1[it][t]; }
        o = pack8(x);
      }
      *(us8*)&Hs[sw(r, ch * 8)] = o;
    }
  }
  __syncthreads();   // staging barrier

  // ---- hoist adj edge types: 4 rows x 7 cols -> 7 byte-packed u32 ----
  unsigned tpk[7];
#pragma unroll
  for (int nt = 0; nt < 7; ++nt) {
    int j = nt * 16 + c;
    int jc = (j < L_) ? j : L_ - 1;
    unsigned pk = 0;
#pragma unroll
    for (int r4 = 0; r4 < 4; ++r4) {
      int i = mi * 16 + q * 4 + r4;
      int t = adjS[(i < L_ ? i : L_ - 1) * 100 + jc];
      t = (i < L_ && j < L_) ? t : 0;
      pk |= ((unsigned)t) << (8 * r4);
    }
    tpk[nt] = pk;
  }

  float lg[7][4];
#pragma unroll
  for (int nt = 0; nt < 7; ++nt)
#pragma unroll
    for (int r4 = 0; r4 < 4; ++r4) lg[nt][r4] = -9e15f;

  // ---- E phase: head-outer, 4 fully-unrolled passes (r2-proven, <=64 regs) ----
#pragma unroll
  for (int k = 0; k < 4; ++k) {
    us8 Afk[4];   // pass-local, 16 VGPRs
#pragma unroll
    for (int ks = 0; ks < 4; ++ks) {
      us8 hr = *(const us8*)&Hs[sw(mi * 16 + c, ks * 32 + q * 8)];
      const float* ap = &aVf[k * 128 + ks * 32 + q * 8];
      f4v av0 = *(const f4v*)ap;
      f4v av1 = *(const f4v*)(ap + 4);
      float pr[8];
#pragma unroll
      for (int t = 0; t < 4; ++t) {
        pr[t]     = b2f(hr[t])     * av0[t];
        pr[4 + t] = b2f(hr[4 + t]) * av1[t];
      }
      Afk[ks] = pack8(pr);
    }
#pragma unroll
    for (int nt = 0; nt < 7; ++nt) {
      f4 acc = {0, 0, 0, 0};
#pragma unroll
      for (int ks = 0; ks < 4; ++ks) {
        bf8 bb = __builtin_bit_cast(bf8, *(const us8*)&Hs[sw(nt * 16 + c, ks * 32 + q * 8)]);
        acc = __builtin_amdgcn_mfma_f32_16x16x32_bf16(__builtin_bit_cast(bf8, Afk[ks]), bb, acc, 0, 0, 0);
      }
#pragma unroll
      for (int r4 = 0; r4 < 4; ++r4) {
        int t = (int)((tpk[nt] >> (8 * r4)) & 255u);
        float e = acc[r4];
        e = (e > 0.f) ? e : 0.2f * e;               // leaky_relu(0.2)
        lg[nt][r4] = (t == k + 1) ? e : lg[nt][r4]; // cndmask, no branch
      }
    }
    __builtin_amdgcn_sched_barrier(0);   // keep each pass's Afk build local
  }

  // ---- in-register softmax -> Pw (same-wave region of Pt) ----
  ushort_t* Pw = Pt + w * 16 * SP_;
#pragma unroll
  for (int r4 = 0; r4 < 4; ++r4) {
    float m = lg[0][r4];
#pragma unroll
    for (int nt = 1; nt < 7; ++nt) m = fmaxf(m, lg[nt][r4]);
#pragma unroll
    for (int off = 1; off <= 8; off <<= 1) m = fmaxf(m, __shfl_xor(m, off, 64));
    float ex[7], s = 0.f;
#pragma unroll
    for (int nt = 0; nt < 7; ++nt) { ex[nt] = __expf(lg[nt][r4] - m); s += ex[nt]; }
#pragma unroll
    for (int off = 1; off <= 8; off <<= 1) s += __shfl_xor(s, off, 64);
    float inv = 1.0f / s;
    int row = q * 4 + r4;
#pragma unroll
    for (int nt = 0; nt < 7; ++nt) Pw[row * SP_ + nt * 16 + c] = f2b(ex[nt] * inv);
  }
#pragma unroll
  for (int t = 0; t < 4; ++t) Pw[c * SP_ + 112 + q * 4 + t] = 0;   // zero K-pad 112..127

  __syncthreads();   // all E reads of Hs done

  // ---- in-place transpose of Hs (disjoint pair swaps; r2-proven) ----
  for (int u = tid; u < 8192; u += 448) {
    int d0 = u >> 7, j0 = u & 127;
    bool up = (j0 > d0);
    int d = up ? d0 : 127 - d0;
    int j = up ? j0 : 127 - j0;
    int ia = sw(d, j), ib = sw(j, d);
    ushort_t va = Hs[ia], vb = Hs[ib];
    Hs[ia] = vb; Hs[ib] = va;
  }
  __syncthreads();   // Hs now holds H^T

  // ---- PV: accumulate all 8 n-tiles into registers ----
  us8 Pf[4];
#pragma unroll
  for (int ks = 0; ks < 4; ++ks)
    Pf[ks] = *(const us8*)&Pw[c * SP_ + ks * 32 + q * 8];
  f4 oc[8];
#pragma unroll
  for (int nt2 = 0; nt2 < 8; ++nt2) {
    f4 a = {0, 0, 0, 0};
#pragma unroll
    for (int ks = 0; ks < 4; ++ks) {
      bf8 ob = __builtin_bit_cast(bf8, *(const us8*)&Hs[sw(nt2 * 16 + c, ks * 32 + q * 8)]);
      a = __builtin_amdgcn_mfma_f32_16x16x32_bf16(__builtin_bit_cast(bf8, Pf[ks]), ob, a, 0, 0, 0);
    }
    oc[nt2] = a;
  }
  __syncthreads();   // all Hs/Pt reads complete block-wide; safe to alias

  // ---- stage to LDS row-major, then fully-coalesced dwordx4 stores ----
  float* Ot = (float*)smem;                    // wave w region: [w*16*SO_, ...)
#pragma unroll
  for (int nt2 = 0; nt2 < 8; ++nt2)
#pragma unroll
    for (int r4 = 0; r4 < 4; ++r4)
      Ot[(w * 16 + q * 4 + r4) * SO_ + nt2 * 16 + c] = oc[nt2][r4];
  // same-wave LDS RAW: compiler inserts lgkmcnt; no barrier needed.
#pragma unroll
  for (int it = 0; it < 8; ++it) {
    int u = it * 64 + lane;                    // wave-local: 16 rows x 32 f4-chunks
    int row16 = u >> 5, col4 = u & 31;
    int i = w * 16 + row16;
    if (i < L_) {
      f4 vv = *(const f4*)&Ot[(w * 16 + row16) * SO_ + col4 * 4];
      *(f4*)&outG[((size_t)b * L_ + i) * D_ + col4 * 4] = vv;
    }
  }
}

extern "C" void kernel_launch(void* const* d_in, const int* in_sizes, int n_in,
                              void* d_out, int out_size, void* d_ws, size_t ws_size,
                              hipStream_t stream) {
  (void)d_ws; (void)ws_size; (void)out_size;
  const int* inp = nullptr; const int* adj = nullptr;
  const float* emb = nullptr; const float* aP[4] = {nullptr, nullptr, nullptr, nullptr};
  int na = 0;
  for (int i = 0; i < n_in; ++i) {
    int s = in_sizes[i];
    if (s == 25600000)            emb = (const float*)d_in[i];
    else if (s == 5120000)        adj = (const int*)d_in[i];
    else if (s == 128 && na < 4)  aP[na++] = (const float*)d_in[i];
    else if (s == 51200 && !inp)  inp = (const int*)d_in[i];
  }
  CombineGraph_fused<<<dim3(B_), dim3(448), 0, stream>>>(
      inp, adj, emb, aP[0], aP[1], aP[2], aP[3], (float*)d_out);
}

// Round 10
// 186.523 us; speedup vs baseline: 1.1586x; 1.0111x over previous
//
#include <hip/hip_runtime.h>
#include <hip/hip_bf16.h>

#define B_  512
#define L_  100
#define D_  128
#define SP_ 136      // Pt ushort stride
#define SO_ 132      // Ot float stride (528 B rows: 16B-aligned, 2-way max bank alias)

typedef unsigned short ushort_t;
typedef __attribute__((ext_vector_type(8))) unsigned short us8;
typedef __attribute__((ext_vector_type(8))) __bf16 bf8;
typedef __attribute__((ext_vector_type(4))) float f4;
typedef __attribute__((ext_vector_type(4))) float f4v;
typedef __attribute__((ext_vector_type(4))) int i4v;
typedef __attribute__((ext_vector_type(4))) unsigned int ui4;

__device__ __forceinline__ float b2f(ushort_t u) {
  union { unsigned i; float f; } v; v.i = ((unsigned)u) << 16; return v.f;
}
__device__ __forceinline__ ushort_t f2b(float f) {
  unsigned u = __float_as_uint(f);
  u += 0x7fffu + ((u >> 16) & 1u);   // RNE
  return (ushort_t)(u >> 16);
}
__device__ __forceinline__ us8 pack8(const float* x) {
  union { __hip_bfloat162 h; unsigned u; } cv;
  ui4 pk;
#pragma unroll
  for (int t = 0; t < 4; ++t) {
    cv.h = __float22bfloat162_rn(make_float2(x[2 * t], x[2 * t + 1]));
    pk[t] = cv.u;
  }
  return __builtin_bit_cast(us8, pk);
}
// XOR-swizzled Hs index (16B chunks contiguous; chunk ^= row&15)
__device__ __forceinline__ int sw(int row, int col) {
  return row * 128 + ((((col >> 3) ^ row) & 15) << 3) + (col & 7);
}
// HsT swizzle: chunk ^= (d&15)^((d>>3)&15). Bijective per row (same function
// used by writer and reader -> placement-consistent by construction). The
// (d>>3) term makes the STAGING write pattern (d = 8*ch+t across 16 lanes)
// hit 16 distinct chunks (2-way banks, free); the (d&15) term keeps the PV
// read pattern (d = nt2*16+c) at 16 distinct chunks too (verified: the two
// c>>3 half-octets land in disjoint chunk octets for every nt2).
__device__ __forceinline__ int swT(int d, int col) {
  int mix = (d & 15) ^ ((d >> 3) & 15);
  return d * 128 + ((((col >> 3) ^ mix) & 15) << 3) + (col & 7);
}

// One block per batch, 448 threads = 7 waves; wave w owns M-tile w.
// smem pool carve (bytes):
//   [0,     32768)  Hs   128x128 bf16 sw()-swizzled (H row-major)
//   [32768, 65536)  HsT  128x128 bf16 swT()-swizzled (H^T, written at staging)
//   [65536, 75536)  adjS 100x100 u8
//   [75536, 77584)  aVf  4x128 f32
// Aliases: Pt (7x16xSP_ bf16, 30464 B) aliases Hs [0,30464) after bar2
// (all E reads of Hs complete). Ot (f32, SO_, 59136 B) aliases [0,59136)
// after bar3 (all HsT/Pt reads complete).
//
// r10: TRANSPOSE PHASE DELETED. H^T is built during staging by dual-writing
// each thread's 8-elem row chunk (row-major b128 -> Hs, 8x ds_write_u16 ->
// HsT via swT). Saves 76 LDS u16 ops/wave + TWO barriers (5 -> 3).
// Everything else (pipelined phase-0, E 4-pass head-outer, in-reg softmax,
// PV) is byte-identical math to the passing r9 kernel.
// Register discipline: every phase's arch-VGPR live set <= ~60
// (empirical spill line at 64 arch; r0/r1/r3 spilled past it).
__global__ __launch_bounds__(448, 4)
void CombineGraph_fused(const int* __restrict__ inp, const int* __restrict__ adjG,
                        const float* __restrict__ embF,
                        const float* __restrict__ a0F, const float* __restrict__ a1F,
                        const float* __restrict__ a2F, const float* __restrict__ a3F,
                        float* __restrict__ outG) {
  __shared__ __align__(16) unsigned char smem[77584];
  ushort_t* Hs = (ushort_t*)smem;
  ushort_t* HsT = (ushort_t*)(smem + 32768);
  unsigned char* adjS = smem + 65536;
  float* aVf = (float*)(smem + 75536);

  const int b = blockIdx.x, tid = threadIdx.x;
  const int w = tid / 64, lane = tid & 63, c = lane & 15, q = lane >> 4;
  const int mi = w;

  // ---- phase 0a: issue emb row-index loads (5 regs) ----
  int idxv[5];
#pragma unroll
  for (int it = 0; it < 5; ++it) {
    int u = tid + it * 448;
    int r = u >> 4;
    idxv[it] = (u < 2048 && r < L_) ? inp[b * L_ + r] : 0;
  }

  // ---- phase 0b: adj loads 6-deep (24 regs; peak ~29 with idxv) ----
  i4v av[6];
#pragma unroll
  for (int it = 0; it < 6; ++it) {
    int u = tid + it * 448;
    if (u < 2500) av[it] = *(const i4v*)(adjG + (size_t)b * 10000 + u * 4);
  }

  // ---- phase 0c: stage a_k vectors ----
  for (int u = tid; u < 512; u += 448) {
    int k = u >> 7, d = u & 127;
    const float* ak = (k == 0) ? a0F : (k == 1) ? a1F : (k == 2) ? a2F : a3F;
    aVf[u] = ak[d];
  }

  // ---- phase 0d: pack adj -> uchar4, store to LDS; frees the 24 regs ----
#pragma unroll
  for (int it = 0; it < 6; ++it) {
    int u = tid + it * 448;
    if (u < 2500) {
      i4v v = av[it];
      unsigned pk = (unsigned)(v[0] & 255) | ((unsigned)(v[1] & 255) << 8) |
                    ((unsigned)(v[2] & 255) << 16) | ((unsigned)(v[3] & 255) << 24);
      *(unsigned*)&adjS[u * 4] = pk;
    }
  }
  // fence: keep emb loads below (prevents adj(24) + ev(40) stacking > 64 regs)
  __builtin_amdgcn_sched_barrier(0);

  // ---- phase 0e: emb loads 5-deep (40 regs; nothing else live) ----
  f4v ev0[5], ev1[5];
#pragma unroll
  for (int it = 0; it < 5; ++it) {
    int u = tid + it * 448;
    int r = u >> 4, ch = u & 15;
    if (u < 2048 && r < L_) {
      const float* src = embF + ((size_t)idxv[it] << 7) + ch * 8;
      ev0[it] = *(const f4v*)src;
      ev1[it] = *(const f4v*)(src + 4);
    }
  }
  // ---- phase 0f: convert f32 -> bf16; DUAL-write Hs (row b128) + HsT (8x u16) ----
#pragma unroll
  for (int it = 0; it < 5; ++it) {
    int u = tid + it * 448;
    if (u < 2048) {
      int r = u >> 4, ch = u & 15;
      us8 o = {0, 0, 0, 0, 0, 0, 0, 0};
      if (r < L_) {
        float x[8];
#pragma unroll
        for (int t = 0; t < 4; ++t) { x[t] = ev0[it][t]; x[4 + t] = ev1[it][t]; }
        o = pack8(x);
      }
      *(us8*)&Hs[sw(r, ch * 8)] = o;
#pragma unroll
      for (int t = 0; t < 8; ++t)
        HsT[swT(ch * 8 + t, r)] = o[t];   // H^T[d=ch*8+t][j=r] = h[r][d]
    }
  }
  __syncthreads();   // bar1: staging done (Hs, HsT, adjS, aVf all visible)

  // ---- hoist adj edge types: 4 rows x 7 cols -> 7 byte-packed u32 ----
  unsigned tpk[7];
#pragma unroll
  for (int nt = 0; nt < 7; ++nt) {
    int j = nt * 16 + c;
    int jc = (j < L_) ? j : L_ - 1;
    unsigned pk = 0;
#pragma unroll
    for (int r4 = 0; r4 < 4; ++r4) {
      int i = mi * 16 + q * 4 + r4;
      int t = adjS[(i < L_ ? i : L_ - 1) * 100 + jc];
      t = (i < L_ && j < L_) ? t : 0;
      pk |= ((unsigned)t) << (8 * r4);
    }
    tpk[nt] = pk;
  }

  float lg[7][4];
#pragma unroll
  for (int nt = 0; nt < 7; ++nt)
#pragma unroll
    for (int r4 = 0; r4 < 4; ++r4) lg[nt][r4] = -9e15f;

  // ---- E phase: head-outer, 4 fully-unrolled passes (r2-proven, <=64 regs) ----
#pragma unroll
  for (int k = 0; k < 4; ++k) {
    us8 Afk[4];   // pass-local, 16 VGPRs
#pragma unroll
    for (int ks = 0; ks < 4; ++ks) {
      us8 hr = *(const us8*)&Hs[sw(mi * 16 + c, ks * 32 + q * 8)];
      const float* ap = &aVf[k * 128 + ks * 32 + q * 8];
      f4v av0 = *(const f4v*)ap;
      f4v av1 = *(const f4v*)(ap + 4);
      float pr[8];
#pragma unroll
      for (int t = 0; t < 4; ++t) {
        pr[t]     = b2f(hr[t])     * av0[t];
        pr[4 + t] = b2f(hr[4 + t]) * av1[t];
      }
      Afk[ks] = pack8(pr);
    }
#pragma unroll
    for (int nt = 0; nt < 7; ++nt) {
      f4 acc = {0, 0, 0, 0};
#pragma unroll
      for (int ks = 0; ks < 4; ++ks) {
        bf8 bb = __builtin_bit_cast(bf8, *(const us8*)&Hs[sw(nt * 16 + c, ks * 32 + q * 8)]);
        acc = __builtin_amdgcn_mfma_f32_16x16x32_bf16(__builtin_bit_cast(bf8, Afk[ks]), bb, acc, 0, 0, 0);
      }
#pragma unroll
      for (int r4 = 0; r4 < 4; ++r4) {
        int t = (int)((tpk[nt] >> (8 * r4)) & 255u);
        float e = acc[r4];
        e = (e > 0.f) ? e : 0.2f * e;               // leaky_relu(0.2)
        lg[nt][r4] = (t == k + 1) ? e : lg[nt][r4]; // cndmask, no branch
      }
    }
    __builtin_amdgcn_sched_barrier(0);   // keep each pass's Afk build local
  }

  __syncthreads();   // bar2: ALL waves' E reads of Hs done -> Pt may alias Hs

  // ---- in-register softmax -> Pw (aliases Hs region; own-wave stripe) ----
  ushort_t* Pw = (ushort_t*)smem + w * 16 * SP_;
#pragma unroll
  for (int r4 = 0; r4 < 4; ++r4) {
    float m = lg[0][r4];
#pragma unroll
    for (int nt = 1; nt < 7; ++nt) m = fmaxf(m, lg[nt][r4]);
#pragma unroll
    for (int off = 1; off <= 8; off <<= 1) m = fmaxf(m, __shfl_xor(m, off, 64));
    float ex[7], s = 0.f;
#pragma unroll
    for (int nt = 0; nt < 7; ++nt) { ex[nt] = __expf(lg[nt][r4] - m); s += ex[nt]; }
#pragma unroll
    for (int off = 1; off <= 8; off <<= 1) s += __shfl_xor(s, off, 64);
    float inv = 1.0f / s;
    int row = q * 4 + r4;
#pragma unroll
    for (int nt = 0; nt < 7; ++nt) Pw[row * SP_ + nt * 16 + c] = f2b(ex[nt] * inv);
  }
#pragma unroll
  for (int t = 0; t < 4; ++t) Pw[c * SP_ + 112 + q * 4 + t] = 0;   // zero K-pad 112..127

  // same-wave cross-lane LDS RAW (writes by lane X, read by lane Y): make
  // the ordering explicit (rule #18).
  asm volatile("s_waitcnt lgkmcnt(0)" ::: "memory");
  __builtin_amdgcn_sched_barrier(0);

  // ---- PV: P rows from Pw, H^T rows straight from HsT (no transpose!) ----
  us8 Pf[4];
#pragma unroll
  for (int ks = 0; ks < 4; ++ks)
    Pf[ks] = *(const us8*)&Pw[c * SP_ + ks * 32 + q * 8];
  f4 oc[8];
#pragma unroll
  for (int nt2 = 0; nt2 < 8; ++nt2) {
    f4 a = {0, 0, 0, 0};
#pragma unroll
    for (int ks = 0; ks < 4; ++ks) {
      bf8 ob = __builtin_bit_cast(bf8, *(const us8*)&HsT[swT(nt2 * 16 + c, ks * 32 + q * 8)]);
      a = __builtin_amdgcn_mfma_f32_16x16x32_bf16(__builtin_bit_cast(bf8, Pf[ks]), ob, a, 0, 0, 0);
    }
    oc[nt2] = a;
  }
  __syncthreads();   // bar3: all HsT/Pt reads complete block-wide; safe to alias

  // ---- stage to LDS row-major, then fully-coalesced dwordx4 stores ----
  float* Ot = (float*)smem;                    // wave w region: [w*16*SO_, ...)
#pragma unroll
  for (int nt2 = 0; nt2 < 8; ++nt2)
#pragma unroll
    for (int r4 = 0; r4 < 4; ++r4)
      Ot[(w * 16 + q * 4 + r4) * SO_ + nt2 * 16 + c] = oc[nt2][r4];
  // same-wave LDS RAW: compiler inserts lgkmcnt; no barrier needed.
#pragma unroll
  for (int it = 0; it < 8; ++it) {
    int u = it * 64 + lane;                    // wave-local: 16 rows x 32 f4-chunks
    int row16 = u >> 5, col4 = u & 31;
    int i = w * 16 + row16;
    if (i < L_) {
      f4 vv = *(const f4*)&Ot[(w * 16 + row16) * SO_ + col4 * 4];
      *(f4*)&outG[((size_t)b * L_ + i) * D_ + col4 * 4] = vv;
    }
  }
}

extern "C" void kernel_launch(void* const* d_in, const int* in_sizes, int n_in,
                              void* d_out, int out_size, void* d_ws, size_t ws_size,
                              hipStream_t stream) {
  (void)d_ws; (void)ws_size; (void)out_size;
  const int* inp = nullptr; const int* adj = nullptr;
  const float* emb = nullptr; const float* aP[4] = {nullptr, nullptr, nullptr, nullptr};
  int na = 0;
  for (int i = 0; i < n_in; ++i) {
    int s = in_sizes[i];
    if (s == 25600000)            emb = (const float*)d_in[i];
    else if (s == 5120000)        adj = (const int*)d_in[i];
    else if (s == 128 && na < 4)  aP[na++] = (const float*)d_in[i];
    else if (s == 51200 && !inp)  inp = (const int*)d_in[i];
  }
  CombineGraph_fused<<<dim3(B_), dim3(448), 0, stream>>>(
      inp, adj, emb, aP[0], aP[1], aP[2], aP[3], (float*)d_out);
}

// Round 11
// 184.338 us; speedup vs baseline: 1.1723x; 1.0119x over previous
//
#include <hip/hip_runtime.h>
#include <hip/hip_bf16.h>

#define B_  512
#define L_  100
#define D_  128
#define SP_ 136      // Pt ushort stride
typedef unsigned short ushort_t;
typedef __attribute__((ext_vector_type(8))) unsigned short us8;
typedef __attribute__((ext_vector_type(8))) __bf16 bf8;
typedef __attribute__((ext_vector_type(4))) float f4;
typedef __attribute__((ext_vector_type(4))) float f4v;
typedef __attribute__((ext_vector_type(4))) unsigned int ui4;

__device__ __forceinline__ float b2f(ushort_t u) {
  union { unsigned i; float f; } v; v.i = ((unsigned)u) << 16; return v.f;
}
__device__ __forceinline__ ushort_t f2b(float f) {
  unsigned u = __float_as_uint(f);
  u += 0x7fffu + ((u >> 16) & 1u);   // RNE
  return (ushort_t)(u >> 16);
}
__device__ __forceinline__ us8 pack8(const float* x) {
  union { __hip_bfloat162 h; unsigned u; } cv;
  ui4 pk;
#pragma unroll
  for (int t = 0; t < 4; ++t) {
    cv.h = __float22bfloat162_rn(make_float2(x[2 * t], x[2 * t + 1]));
    pk[t] = cv.u;
  }
  return __builtin_bit_cast(us8, pk);
}
// XOR-swizzled Hs index (16B chunks contiguous; chunk ^= row&15)
__device__ __forceinline__ int sw(int row, int col) {
  return row * 128 + ((((col >> 3) ^ row) & 15) << 3) + (col & 7);
}
// HsT swizzle: chunk ^= (d&15)^((d>>3)&15); bijective, same fn for writer+reader.
__device__ __forceinline__ int swT(int d, int col) {
  int mix = (d & 15) ^ ((d >> 3) & 15);
  return d * 128 + ((((col >> 3) ^ mix) & 15) << 3) + (col & 7);
}

// One block per batch, 448 threads = 7 waves; wave w owns M-tile w.
// smem pool carve (bytes):
//   [0,     32768)  Hs   128x128 bf16 sw()-swizzled (rows 0..111 staged; rest unused)
//   [32768, 65536)  HsT  128x128 bf16 swT()-swizzled (H^T, written at staging)
//   [65536, 67584)  aVf  4x128 f32
// Pt (7x16xSP_ bf16, 30464 B) aliases Hs [0,30464) after bar2.
//
// r11 changes vs r10 (each independently safe):
//  * adjS LDS REMOVED: edge types loaded direct global->tpk[7] in phase 0
//    (28 coalesced-per-16-lane loads, packed immediately, fenced pre-emb)
//  * output stored DIRECT from oc regs (no Ot alias, no bar3): 2 barriers total
//  * s_setprio(1) around E/PV MFMA clusters (T5; independent-wave regime)
//  * Hs rows >=112 never written (never read)
// Register discipline: every phase's arch live set <= ~60 (spill line 64).
__global__ __launch_bounds__(448, 4)
void CombineGraph_fused(const int* __restrict__ inp, const int* __restrict__ adjG,
                        const float* __restrict__ embF,
                        const float* __restrict__ a0F, const float* __restrict__ a1F,
                        const float* __restrict__ a2F, const float* __restrict__ a3F,
                        float* __restrict__ outG) {
  __shared__ __align__(16) unsigned char smem[67584];
  ushort_t* Hs = (ushort_t*)smem;
  ushort_t* HsT = (ushort_t*)(smem + 32768);
  float* aVf = (float*)(smem + 65536);

  const int b = blockIdx.x, tid = threadIdx.x;
  const int w = tid / 64, lane = tid & 63, c = lane & 15, q = lane >> 4;
  const int mi = w;

  // ---- phase 0a: issue emb row-index loads (5 regs) ----
  int idxv[5];
#pragma unroll
  for (int it = 0; it < 5; ++it) {
    int u = tid + it * 448;
    int r = u >> 4;
    idxv[it] = (u < 2048 && r < L_) ? inp[b * L_ + r] : 0;
  }

  // ---- phase 0b: edge types direct global -> tpk[7] (28 loads, packed) ----
  // lane (q,c), row-block r4: i = mi*16+q*4+r4, j = nt*16+c; 16 c-lanes read
  // 64B contiguous. Clamped addresses stay inside batch b's 10000-int block.
  unsigned tpk[7];
#pragma unroll
  for (int nt = 0; nt < 7; ++nt) {
    int j = nt * 16 + c;
    int jc = (j < L_) ? j : L_ - 1;
    unsigned pk = 0;
#pragma unroll
    for (int r4 = 0; r4 < 4; ++r4) {
      int i = mi * 16 + q * 4 + r4;
      int ic = (i < L_) ? i : L_ - 1;
      int t = adjG[(size_t)b * 10000 + ic * 100 + jc];
      t = (i < L_ && j < L_) ? t : 0;
      pk |= ((unsigned)t) << (8 * r4);
    }
    tpk[nt] = pk;
  }

  // ---- phase 0c: stage a_k vectors (2 unrolled guarded writes) ----
  {
    int k = tid >> 7, d = tid & 127;
    const float* ak = (k == 0) ? a0F : (k == 1) ? a1F : (k == 2) ? a2F : a3F;
    aVf[tid] = ak[d];
    int u2 = tid + 448;
    if (u2 < 512) aVf[u2] = a3F[u2 & 127];
  }
  // fence: keep emb loads below (bounds in-flight register stacking)
  __builtin_amdgcn_sched_barrier(0);

  // ---- phase 0e: emb loads 5-deep (40 regs) ----
  f4v ev0[5], ev1[5];
#pragma unroll
  for (int it = 0; it < 5; ++it) {
    int u = tid + it * 448;
    int r = u >> 4, ch = u & 15;
    if (u < 2048 && r < L_) {
      const float* src = embF + ((size_t)idxv[it] << 7) + ch * 8;
      ev0[it] = *(const f4v*)src;
      ev1[it] = *(const f4v*)(src + 4);
    }
  }
  // ---- phase 0f: convert f32 -> bf16; write Hs (rows<112) + HsT (8x u16) ----
#pragma unroll
  for (int it = 0; it < 5; ++it) {
    int u = tid + it * 448;
    if (u < 2048) {
      int r = u >> 4, ch = u & 15;
      us8 o = {0, 0, 0, 0, 0, 0, 0, 0};
      if (r < L_) {
        float x[8];
#pragma unroll
        for (int t = 0; t < 4; ++t) { x[t] = ev0[it][t]; x[4 + t] = ev1[it][t]; }
        o = pack8(x);
      }
      if (r < 112) *(us8*)&Hs[sw(r, ch * 8)] = o;   // rows >=112 never read
#pragma unroll
      for (int t = 0; t < 8; ++t)
        HsT[swT(ch * 8 + t, r)] = o[t];             // H^T[d][j=r]
    }
  }
  __syncthreads();   // bar1: staging done (Hs, HsT, aVf visible)

  float lg[7][4];
#pragma unroll
  for (int nt = 0; nt < 7; ++nt)
#pragma unroll
    for (int r4 = 0; r4 < 4; ++r4) lg[nt][r4] = -9e15f;

  // ---- E phase: head-outer, 4 fully-unrolled passes (r2-proven, <=64 regs) ----
#pragma unroll
  for (int k = 0; k < 4; ++k) {
    us8 Afk[4];   // pass-local, 16 VGPRs
#pragma unroll
    for (int ks = 0; ks < 4; ++ks) {
      us8 hr = *(const us8*)&Hs[sw(mi * 16 + c, ks * 32 + q * 8)];
      const float* ap = &aVf[k * 128 + ks * 32 + q * 8];
      f4v av0 = *(const f4v*)ap;
      f4v av1 = *(const f4v*)(ap + 4);
      float pr[8];
#pragma unroll
      for (int t = 0; t < 4; ++t) {
        pr[t]     = b2f(hr[t])     * av0[t];
        pr[4 + t] = b2f(hr[4 + t]) * av1[t];
      }
      Afk[ks] = pack8(pr);
    }
    __builtin_amdgcn_s_setprio(1);
#pragma unroll
    for (int nt = 0; nt < 7; ++nt) {
      f4 acc = {0, 0, 0, 0};
#pragma unroll
      for (int ks = 0; ks < 4; ++ks) {
        bf8 bb = __builtin_bit_cast(bf8, *(const us8*)&Hs[sw(nt * 16 + c, ks * 32 + q * 8)]);
        acc = __builtin_amdgcn_mfma_f32_16x16x32_bf16(__builtin_bit_cast(bf8, Afk[ks]), bb, acc, 0, 0, 0);
      }
#pragma unroll
      for (int r4 = 0; r4 < 4; ++r4) {
        int t = (int)((tpk[nt] >> (8 * r4)) & 255u);
        float e = acc[r4];
        e = (e > 0.f) ? e : 0.2f * e;               // leaky_relu(0.2)
        lg[nt][r4] = (t == k + 1) ? e : lg[nt][r4]; // cndmask, no branch
      }
    }
    __builtin_amdgcn_s_setprio(0);
    __builtin_amdgcn_sched_barrier(0);   // keep each pass's Afk build local
  }

  __syncthreads();   // bar2: all waves' E reads of Hs done -> Pt may alias Hs

  // ---- in-register softmax -> Pw (aliases Hs region; own-wave stripe) ----
  ushort_t* Pw = (ushort_t*)smem + w * 16 * SP_;
#pragma unroll
  for (int r4 = 0; r4 < 4; ++r4) {
    float m = lg[0][r4];
#pragma unroll
    for (int nt = 1; nt < 7; ++nt) m = fmaxf(m, lg[nt][r4]);
#pragma unroll
    for (int off = 1; off <= 8; off <<= 1) m = fmaxf(m, __shfl_xor(m, off, 64));
    float ex[7], s = 0.f;
#pragma unroll
    for (int nt = 0; nt < 7; ++nt) { ex[nt] = __expf(lg[nt][r4] - m); s += ex[nt]; }
#pragma unroll
    for (int off = 1; off <= 8; off <<= 1) s += __shfl_xor(s, off, 64);
    float inv = 1.0f / s;
    int row = q * 4 + r4;
#pragma unroll
    for (int nt = 0; nt < 7; ++nt) Pw[row * SP_ + nt * 16 + c] = f2b(ex[nt] * inv);
  }
#pragma unroll
  for (int t = 0; t < 4; ++t) Pw[c * SP_ + 112 + q * 4 + t] = 0;   // zero K-pad 112..127

  // same-wave cross-lane LDS RAW: make ordering explicit (rule #18).
  asm volatile("s_waitcnt lgkmcnt(0)" ::: "memory");
  __builtin_amdgcn_sched_barrier(0);

  // ---- PV: P rows from Pw, H^T rows straight from HsT ----
  us8 Pf[4];
#pragma unroll
  for (int ks = 0; ks < 4; ++ks)
    Pf[ks] = *(const us8*)&Pw[c * SP_ + ks * 32 + q * 8];
  f4 oc[8];
  __builtin_amdgcn_s_setprio(1);
#pragma unroll
  for (int nt2 = 0; nt2 < 8; ++nt2) {
    f4 a = {0, 0, 0, 0};
#pragma unroll
    for (int ks = 0; ks < 4; ++ks) {
      bf8 ob = __builtin_bit_cast(bf8, *(const us8*)&HsT[swT(nt2 * 16 + c, ks * 32 + q * 8)]);
      a = __builtin_amdgcn_mfma_f32_16x16x32_bf16(__builtin_bit_cast(bf8, Pf[ks]), ob, a, 0, 0, 0);
    }
    oc[nt2] = a;
  }
  __builtin_amdgcn_s_setprio(0);

  // ---- direct global stores (no LDS round-trip, no barrier) ----
  // lane (q,c) owns rows i = w*16+q*4+r4, col d = nt2*16+c: 16-lane groups
  // write 64B contiguous; 4 segments per instr.
#pragma unroll
  for (int r4 = 0; r4 < 4; ++r4) {
    int i = w * 16 + q * 4 + r4;
    if (i < L_) {
      float* dst = outG + ((size_t)b * L_ + i) * D_ + c;
#pragma unroll
      for (int nt2 = 0; nt2 < 8; ++nt2)
        dst[nt2 * 16] = oc[nt2][r4];
    }
  }
}

extern "C" void kernel_launch(void* const* d_in, const int* in_sizes, int n_in,
                              void* d_out, int out_size, void* d_ws, size_t ws_size,
                              hipStream_t stream) {
  (void)d_ws; (void)ws_size; (void)out_size;
  const int* inp = nullptr; const int* adj = nullptr;
  const float* emb = nullptr; const float* aP[4] = {nullptr, nullptr, nullptr, nullptr};
  int na = 0;
  for (int i = 0; i < n_in; ++i) {
    int s = in_sizes[i];
    if (s == 25600000)            emb = (const float*)d_in[i];
    else if (s == 5120000)        adj = (const int*)d_in[i];
    else if (s == 128 && na < 4)  aP[na++] = (const float*)d_in[i];
    else if (s == 51200 && !inp)  inp = (const int*)d_in[i];
  }
  CombineGraph_fused<<<dim3(B_), dim3(448), 0, stream>>>(
      inp, adj, emb, aP[0], aP[1], aP[2], aP[3], (float*)d_out);
}

// Round 12
// 182.948 us; speedup vs baseline: 1.1812x; 1.0076x over previous
//
#include <hip/hip_runtime.h>
#include <hip/hip_bf16.h>

#define B_  512
#define L_  100
#define D_  128
#define SP_ 136      // Pt ushort stride
typedef unsigned short ushort_t;
typedef __attribute__((ext_vector_type(8))) unsigned short us8;
typedef __attribute__((ext_vector_type(8))) __bf16 bf8;
typedef __attribute__((ext_vector_type(4))) float f4;
typedef __attribute__((ext_vector_type(4))) float f4v;
typedef __attribute__((ext_vector_type(4))) unsigned int ui4;

__device__ __forceinline__ float b2f(ushort_t u) {
  union { unsigned i; float f; } v; v.i = ((unsigned)u) << 16; return v.f;
}
__device__ __forceinline__ ushort_t f2b(float f) {
  unsigned u = __float_as_uint(f);
  u += 0x7fffu + ((u >> 16) & 1u);   // RNE
  return (ushort_t)(u >> 16);
}
__device__ __forceinline__ us8 pack8(const float* x) {
  union { __hip_bfloat162 h; unsigned u; } cv;
  ui4 pk;
#pragma unroll
  for (int t = 0; t < 4; ++t) {
    cv.h = __float22bfloat162_rn(make_float2(x[2 * t], x[2 * t + 1]));
    pk[t] = cv.u;
  }
  return __builtin_bit_cast(us8, pk);
}
// XOR-swizzled Hs index (16B chunks contiguous; chunk ^= row&15)
__device__ __forceinline__ int sw(int row, int col) {
  return row * 128 + ((((col >> 3) ^ row) & 15) << 3) + (col & 7);
}
// HsT swizzle: chunk ^= (d&15)^((d>>3)&15); bijective, same fn for writer+reader.
__device__ __forceinline__ int swT(int d, int col) {
  int mix = (d & 15) ^ ((d >> 3) & 15);
  return d * 128 + ((((col >> 3) ^ mix) & 15) << 3) + (col & 7);
}

// One block per batch, 448 threads = 7 waves; wave w owns M-tile w.
// smem pool carve (bytes):
//   [0,     32768)  Hs   128x128 bf16 sw()-swizzled (rows 0..111 staged)
//   [32768, 65536)  HsT  128x128 bf16 swT()-swizzled (H^T, written at staging)
//   [65536, 67584)  aVf  4x128 f32
// Pt (7x16xSP_ bf16, 30464 B) aliases Hs [0,30464) after bar2.
//
// r12 = r11 + E phase switched 4-head-outer -> 2-HEAD-outer (two fully
// unrolled passes, Af2[2][4]=32 regs pass-local, cndmask lg updates,
// sched_barrier between passes): halves the B-side LDS re-reads
// (112 -> 56 ds_read_b128/wave), the dominant LDS-pipe slice.
// Unlike r1 (dynamic loop + RMW) and r3 (phase-0 stacking), this keeps
// every phase's live set bounded: peak ~91 unified regs < 128 cap.
// Falsifier: WRITE_SIZE > 35 MB = spill -> revert to 4-pass.
__global__ __launch_bounds__(448, 4)
void CombineGraph_fused(const int* __restrict__ inp, const int* __restrict__ adjG,
                        const float* __restrict__ embF,
                        const float* __restrict__ a0F, const float* __restrict__ a1F,
                        const float* __restrict__ a2F, const float* __restrict__ a3F,
                        float* __restrict__ outG) {
  __shared__ __align__(16) unsigned char smem[67584];
  ushort_t* Hs = (ushort_t*)smem;
  ushort_t* HsT = (ushort_t*)(smem + 32768);
  float* aVf = (float*)(smem + 65536);

  const int b = blockIdx.x, tid = threadIdx.x;
  const int w = tid / 64, lane = tid & 63, c = lane & 15, q = lane >> 4;
  const int mi = w;

  // ---- phase 0a: issue emb row-index loads (5 regs) ----
  int idxv[5];
#pragma unroll
  for (int it = 0; it < 5; ++it) {
    int u = tid + it * 448;
    int r = u >> 4;
    idxv[it] = (u < 2048 && r < L_) ? inp[b * L_ + r] : 0;
  }

  // ---- phase 0b: edge types direct global -> tpk[7] (28 loads, packed) ----
  unsigned tpk[7];
#pragma unroll
  for (int nt = 0; nt < 7; ++nt) {
    int j = nt * 16 + c;
    int jc = (j < L_) ? j : L_ - 1;
    unsigned pk = 0;
#pragma unroll
    for (int r4 = 0; r4 < 4; ++r4) {
      int i = mi * 16 + q * 4 + r4;
      int ic = (i < L_) ? i : L_ - 1;
      int t = adjG[(size_t)b * 10000 + ic * 100 + jc];
      t = (i < L_ && j < L_) ? t : 0;
      pk |= ((unsigned)t) << (8 * r4);
    }
    tpk[nt] = pk;
  }

  // ---- phase 0c: stage a_k vectors ----
  {
    int k = tid >> 7, d = tid & 127;
    const float* ak = (k == 0) ? a0F : (k == 1) ? a1F : (k == 2) ? a2F : a3F;
    aVf[tid] = ak[d];
    int u2 = tid + 448;
    if (u2 < 512) aVf[u2] = a3F[u2 & 127];
  }
  // fence: keep emb loads below (bounds in-flight register stacking)
  __builtin_amdgcn_sched_barrier(0);

  // ---- phase 0e: emb loads 5-deep (40 regs) ----
  f4v ev0[5], ev1[5];
#pragma unroll
  for (int it = 0; it < 5; ++it) {
    int u = tid + it * 448;
    int r = u >> 4, ch = u & 15;
    if (u < 2048 && r < L_) {
      const float* src = embF + ((size_t)idxv[it] << 7) + ch * 8;
      ev0[it] = *(const f4v*)src;
      ev1[it] = *(const f4v*)(src + 4);
    }
  }
  // ---- phase 0f: convert f32 -> bf16; write Hs (rows<112) + HsT (8x u16) ----
#pragma unroll
  for (int it = 0; it < 5; ++it) {
    int u = tid + it * 448;
    if (u < 2048) {
      int r = u >> 4, ch = u & 15;
      us8 o = {0, 0, 0, 0, 0, 0, 0, 0};
      if (r < L_) {
        float x[8];
#pragma unroll
        for (int t = 0; t < 4; ++t) { x[t] = ev0[it][t]; x[4 + t] = ev1[it][t]; }
        o = pack8(x);
      }
      if (r < 112) *(us8*)&Hs[sw(r, ch * 8)] = o;   // rows >=112 never read
#pragma unroll
      for (int t = 0; t < 8; ++t)
        HsT[swT(ch * 8 + t, r)] = o[t];             // H^T[d][j=r]
    }
  }
  __syncthreads();   // bar1: staging done (Hs, HsT, aVf visible)

  float lg[7][4];
#pragma unroll
  for (int nt = 0; nt < 7; ++nt)
#pragma unroll
    for (int r4 = 0; r4 < 4; ++r4) lg[nt][r4] = -9e15f;

  // ---- E phase: 2-head-outer, two fully-unrolled passes ----
#pragma unroll
  for (int p = 0; p < 2; ++p) {
    us8 Af2[2][4];   // pass-local: 32 VGPRs
#pragma unroll
    for (int ks = 0; ks < 4; ++ks) {
      us8 hr = *(const us8*)&Hs[sw(mi * 16 + c, ks * 32 + q * 8)];
      float hfv[8];
#pragma unroll
      for (int jj = 0; jj < 8; ++jj) hfv[jj] = b2f(hr[jj]);
#pragma unroll
      for (int kk = 0; kk < 2; ++kk) {
        const float* ap = &aVf[(p * 2 + kk) * 128 + ks * 32 + q * 8];
        f4v av0 = *(const f4v*)ap;
        f4v av1 = *(const f4v*)(ap + 4);
        float pr[8];
#pragma unroll
        for (int t = 0; t < 4; ++t) {
          pr[t]     = hfv[t]     * av0[t];
          pr[4 + t] = hfv[4 + t] * av1[t];
        }
        Af2[kk][ks] = pack8(pr);
      }
    }
    __builtin_amdgcn_s_setprio(1);
#pragma unroll
    for (int nt = 0; nt < 7; ++nt) {
      f4 ac0 = {0, 0, 0, 0}, ac1 = {0, 0, 0, 0};
#pragma unroll
      for (int ks = 0; ks < 4; ++ks) {
        bf8 bb = __builtin_bit_cast(bf8, *(const us8*)&Hs[sw(nt * 16 + c, ks * 32 + q * 8)]);
        ac0 = __builtin_amdgcn_mfma_f32_16x16x32_bf16(__builtin_bit_cast(bf8, Af2[0][ks]), bb, ac0, 0, 0, 0);
        ac1 = __builtin_amdgcn_mfma_f32_16x16x32_bf16(__builtin_bit_cast(bf8, Af2[1][ks]), bb, ac1, 0, 0, 0);
      }
#pragma unroll
      for (int r4 = 0; r4 < 4; ++r4) {
        int t = (int)((tpk[nt] >> (8 * r4)) & 255u);
        float e0 = ac0[r4]; e0 = (e0 > 0.f) ? e0 : 0.2f * e0;   // leaky(0.2)
        float e1 = ac1[r4]; e1 = (e1 > 0.f) ? e1 : 0.2f * e1;
        lg[nt][r4] = (t == 2 * p + 1) ? e0 : lg[nt][r4];        // cndmask
        lg[nt][r4] = (t == 2 * p + 2) ? e1 : lg[nt][r4];
      }
    }
    __builtin_amdgcn_s_setprio(0);
    __builtin_amdgcn_sched_barrier(0);   // keep each pass's Af2 build local
  }

  __syncthreads();   // bar2: all waves' E reads of Hs done -> Pt may alias Hs

  // ---- in-register softmax -> Pw (aliases Hs region; own-wave stripe) ----
  ushort_t* Pw = (ushort_t*)smem + w * 16 * SP_;
#pragma unroll
  for (int r4 = 0; r4 < 4; ++r4) {
    float m = lg[0][r4];
#pragma unroll
    for (int nt = 1; nt < 7; ++nt) m = fmaxf(m, lg[nt][r4]);
#pragma unroll
    for (int off = 1; off <= 8; off <<= 1) m = fmaxf(m, __shfl_xor(m, off, 64));
    float ex[7], s = 0.f;
#pragma unroll
    for (int nt = 0; nt < 7; ++nt) { ex[nt] = __expf(lg[nt][r4] - m); s += ex[nt]; }
#pragma unroll
    for (int off = 1; off <= 8; off <<= 1) s += __shfl_xor(s, off, 64);
    float inv = 1.0f / s;
    int row = q * 4 + r4;
#pragma unroll
    for (int nt = 0; nt < 7; ++nt) Pw[row * SP_ + nt * 16 + c] = f2b(ex[nt] * inv);
  }
#pragma unroll
  for (int t = 0; t < 4; ++t) Pw[c * SP_ + 112 + q * 4 + t] = 0;   // zero K-pad 112..127

  // same-wave cross-lane LDS RAW: make ordering explicit (rule #18).
  asm volatile("s_waitcnt lgkmcnt(0)" ::: "memory");
  __builtin_amdgcn_sched_barrier(0);

  // ---- PV: P rows from Pw, H^T rows straight from HsT ----
  us8 Pf[4];
#pragma unroll
  for (int ks = 0; ks < 4; ++ks)
    Pf[ks] = *(const us8*)&Pw[c * SP_ + ks * 32 + q * 8];
  f4 oc[8];
  __builtin_amdgcn_s_setprio(1);
#pragma unroll
  for (int nt2 = 0; nt2 < 8; ++nt2) {
    f4 a = {0, 0, 0, 0};
#pragma unroll
    for (int ks = 0; ks < 4; ++ks) {
      bf8 ob = __builtin_bit_cast(bf8, *(const us8*)&HsT[swT(nt2 * 16 + c, ks * 32 + q * 8)]);
      a = __builtin_amdgcn_mfma_f32_16x16x32_bf16(__builtin_bit_cast(bf8, Pf[ks]), ob, a, 0, 0, 0);
    }
    oc[nt2] = a;
  }
  __builtin_amdgcn_s_setprio(0);

  // ---- direct global stores (no LDS round-trip, no barrier) ----
#pragma unroll
  for (int r4 = 0; r4 < 4; ++r4) {
    int i = w * 16 + q * 4 + r4;
    if (i < L_) {
      float* dst = outG + ((size_t)b * L_ + i) * D_ + c;
#pragma unroll
      for (int nt2 = 0; nt2 < 8; ++nt2)
        dst[nt2 * 16] = oc[nt2][r4];
    }
  }
}

extern "C" void kernel_launch(void* const* d_in, const int* in_sizes, int n_in,
                              void* d_out, int out_size, void* d_ws, size_t ws_size,
                              hipStream_t stream) {
  (void)d_ws; (void)ws_size; (void)out_size;
  const int* inp = nullptr; const int* adj = nullptr;
  const float* emb = nullptr; const float* aP[4] = {nullptr, nullptr, nullptr, nullptr};
  int na = 0;
  for (int i = 0; i < n_in; ++i) {
    int s = in_sizes[i];
    if (s == 25600000)            emb = (const float*)d_in[i];
    else if (s == 5120000)        adj = (const int*)d_in[i];
    else if (s == 128 && na < 4)  aP[na++] = (const float*)d_in[i];
    else if (s == 51200 && !inp)  inp = (const int*)d_in[i];
  }
  CombineGraph_fused<<<dim3(B_), dim3(448), 0, stream>>>(
      inp, adj, emb, aP[0], aP[1], aP[2], aP[3], (float*)d_out);
}